// Round 6
// baseline (368.740 us; speedup 1.0000x reference)
//
#include <hip/hip_runtime.h>

#define BATCH 32
#define SEQT  2048
#define INSZ  256
#define RSV   512
#define NSEG  4
#define SEGT  (SEQT / NSEG)    // 512 output timesteps per segment
#define RBLK  32               // r's per block
#define NRB   (RSV / RBLK)     // 16
#define CHT   128              // chunk: u-rows (timesteps) per GEMM/recur phase
#define NCH   (SEGT / CHT)     // 4
#define USTR  40               // Ush row stride (f32): write 4-way conflict, read free
#define WARM  32               // warmup steps (|d|<=0.5 -> err <= 2^-32)

#define K2LOG2E 2.8853900817779268f  // 2*log2(e)

using f16x8 = __attribute__((ext_vector_type(8))) _Float16;
using f16x4 = __attribute__((ext_vector_type(4))) _Float16;
using f32x4 = __attribute__((ext_vector_type(4))) float;

// s' = tanh(d*s + u) via exp2; dK = d*2log2e.
static __device__ __forceinline__ float esn_step(float s, float u, float dK) {
    float z  = __builtin_fmaf(dK, s, u * K2LOG2E);
    float e  = __builtin_amdgcn_exp2f(z);
    float rc = __builtin_amdgcn_rcpf(1.0f + e);
    return __builtin_fmaf(-2.0f, rc, 1.0f);
}

// Fused ESN: block = (b, rb, seg). W[rb] -> LDS f16 hi/lo (XOR-swizzled) once.
// Per 128-t chunk: 4 waves MFMA u (A direct from global, no per-ks barriers),
// u -> LDS fp32, wave0 recurs 128 serial steps (state in regs) while waves 1-3
// run the next chunk's GEMM. 32-step warmup per segment from zero state.
__global__ __launch_bounds__(256) void esn_fused(const float* __restrict__ X,
                                                 const float* __restrict__ W,
                                                 const float* __restrict__ D,
                                                 float* __restrict__ OUT) {
    __shared__ _Float16 Wh[RBLK * INSZ];   // 16 KB, row r at byte r*512, 16B-granule XOR (r&7)<<4
    __shared__ _Float16 Wl[RBLK * INSZ];   // 16 KB
    __shared__ float    Ush[CHT * USTR];   // 20 KB, u[tloc][r], fp32

    const int tid  = threadIdx.x;
    const int lane = tid & 63;
    const int wid  = tid >> 6;

    // chunked XCD swizzle: 16 rb-siblings of one (b,seg) adjacent on one XCD (share X rows in L2)
    const int lg   = (blockIdx.x & 7) * 256 + (blockIdx.x >> 3);
    const int rb   = lg & (NRB - 1);
    const int bseg = lg >> 4;
    const int b    = bseg & 31;
    const int seg  = bseg >> 5;
    const int T0   = seg * SEGT;

    // ---- stage W[rb*32 .. +31][0..255] -> f16 hi/lo, swizzled (one-time) ----
    #pragma unroll
    for (int i = 0; i < 8; ++i) {
        const int idx4 = i * 256 + tid;          // 0..2047 float4-chunks
        const int row  = idx4 >> 6;              // 0..31
        const int col  = (idx4 & 63) * 4;        // 0..252
        float4 v = *(const float4*)(W + (size_t)(rb * RBLK + row) * INSZ + col);
        float w4[4] = {v.x, v.y, v.z, v.w};
        f16x4 h, l;
        #pragma unroll
        for (int j = 0; j < 4; ++j) {
            _Float16 hh = (_Float16)w4[j];
            h[j] = hh;
            l[j] = (_Float16)(w4[j] - (float)hh);
        }
        const int boff = row * 512 + ((col * 2) ^ ((row & 7) << 4));  // XOR on 16B granule
        *(f16x4*)((char*)Wh + boff) = h;
        *(f16x4*)((char*)Wl + boff) = l;
    }

    const float dK = D[rb * RBLK + (lane & 31)] * K2LOG2E;
    float* outBase = OUT + (size_t)b * SEQT * RSV + rb * RBLK + (lane & 31);
    float s = 0.0f;                       // recurrence state (wave0 lanes 0..31)
    const int trow = wid * 32 + (lane & 15);   // this wave's t-row within chunk
    const int q    = lane >> 4;                // 0..3 k-quarter / r-quarter

    __syncthreads();

    // jc = -1: warmup chunk (u-idx T0-127..T0, recur last 32 only, no writes)
    for (int jc = (seg ? -1 : 0); jc < NCH; ++jc) {
        const int c0 = (jc < 0) ? (T0 - CHT + 1) : (T0 + 1 + jc * CHT);  // first u-idx

        // ---- GEMM: u[c0 .. c0+127][rb*32 .. +31], no barriers inside ----
        f32x4 acc[2][2] = {};
        #pragma unroll
        for (int ks = 0; ks < 8; ++ks) {
            f16x8 wfh[2], wfl[2];
            #pragma unroll
            for (int n = 0; n < 2; ++n) {
                const int rrow = n * 16 + (lane & 15);
                const int boff = rrow * 512 + (((ks * 4 + q) * 16) ^ ((rrow & 7) << 4));
                wfh[n] = *(const f16x8*)((const char*)Wh + boff);
                wfl[n] = *(const f16x8*)((const char*)Wl + boff);
            }
            #pragma unroll
            for (int mf = 0; mf < 2; ++mf) {
                int ui = c0 + trow + mf * 16;
                ui = ui < SEQT ? ui : SEQT - 1;          // clamp (dup row, output unused)
                const float* xp = X + ((size_t)b * SEQT + ui) * INSZ + ks * 32 + q * 8;
                float4 x0 = *(const float4*)xp;
                float4 x1 = *(const float4*)(xp + 4);
                float x8[8] = {x0.x, x0.y, x0.z, x0.w, x1.x, x1.y, x1.z, x1.w};
                f16x8 af;
                #pragma unroll
                for (int j = 0; j < 8; ++j) af[j] = (_Float16)x8[j];
                // swapped operands: D row-run (regs) = W rows (r), D col = X rows (t)
                acc[mf][0] = __builtin_amdgcn_mfma_f32_16x16x32_f16(wfh[0], af, acc[mf][0], 0, 0, 0);
                acc[mf][1] = __builtin_amdgcn_mfma_f32_16x16x32_f16(wfh[1], af, acc[mf][1], 0, 0, 0);
                acc[mf][0] = __builtin_amdgcn_mfma_f32_16x16x32_f16(wfl[0], af, acc[mf][0], 0, 0, 0);
                acc[mf][1] = __builtin_amdgcn_mfma_f32_16x16x32_f16(wfl[1], af, acc[mf][1], 0, 0, 0);
            }
        }

        __syncthreads();   // previous chunk's recur has finished reading Ush
        #pragma unroll
        for (int mf = 0; mf < 2; ++mf)
            #pragma unroll
            for (int nf = 0; nf < 2; ++nf) {
                const int tloc = wid * 32 + mf * 16 + (lane & 15);
                const int r0   = nf * 16 + q * 4;        // 4 consecutive r per lane
                *(f32x4*)&Ush[tloc * USTR + r0] = acc[mf][nf];
            }
        __syncthreads();   // Ush ready

        // ---- recurrence: wave0 only; waves 1-3 race ahead into next chunk GEMM ----
        if (wid == 0 && lane < RBLK) {
            if (jc < 0) {
                #pragma unroll 8
                for (int i = CHT - WARM; i < CHT; ++i)
                    s = esn_step(s, Ush[i * USTR + lane], dK);
            } else {
                #pragma unroll 8
                for (int i = 0; i < CHT; ++i) {
                    s = esn_step(s, Ush[i * USTR + lane], dK);
                    const int t = c0 - 1 + i;            // out[t] uses u[t+1]
                    if (t <= SEQT - 2) outBase[(size_t)t * RSV] = s;
                }
            }
        }
    }

    // final timestep is all zeros (reference returns zero tail)
    if (seg == NSEG - 1 && wid == 0 && lane < RBLK)
        outBase[(size_t)(SEQT - 1) * RSV] = 0.0f;
}

extern "C" void kernel_launch(void* const* d_in, const int* in_sizes, int n_in,
                              void* d_out, int out_size, void* d_ws, size_t ws_size,
                              hipStream_t stream) {
    const float* X = (const float*)d_in[0];   // [32,2048,256] fp32
    const float* W = (const float*)d_in[1];   // [512,256] fp32
    const float* D = (const float*)d_in[2];   // [512] fp32
    float* OUT = (float*)d_out;               // [32,2048,512] fp32

    // grid = 32 b * 4 seg * 16 rb = 2048 blocks; no workspace needed.
    esn_fused<<<dim3(BATCH * NSEG * NRB), dim3(256), 0, stream>>>(X, W, D, OUT);
}